// Round 1
// baseline (970.579 us; speedup 1.0000x reference)
//
#include <hip/hip_runtime.h>
#include <math.h>

#define NP 512
#define TT 12

// workspace float offsets
#define OFF_PREV   0        // N*2
#define OFF_CURABS 1024     // [2][N*2] double buffer
#define OFF_H      3072     // N*64
#define OFF_CS     35840    // N*64
#define OFF_CTX    68608    // N*64
#define OFF_A      101376   // N*64  (h @ W1[32:96])
#define OFF_B      134144   // N*64  (h @ W1[96:160])
#define OFF_WIHT   166912   // 128*256 transposed W_ih
#define OFF_WHHT   199680   // 64*256 transposed W_hh
#define OFF_WC     216064   // [2][64]  W_sp @ W1[0:32]
#define OFF_BASE   216192   // [64]     b1 + b_sp @ W1[0:32]
// total 216256 floats = 865 KB

__global__ __launch_bounds__(256) void init_k(
    const float* __restrict__ lastpos, const float* __restrict__ obs,
    const float* __restrict__ h0, const float* __restrict__ c0,
    const float* __restrict__ W_ih, const float* __restrict__ W_hh,
    const float* __restrict__ W_sp, const float* __restrict__ b_sp,
    const float* __restrict__ W1, const float* __restrict__ b1,
    float* __restrict__ ws) {
  int tid = blockIdx.x * 256 + threadIdx.x;   // 128 blocks -> 32768 threads
  if (tid < 1024) {
    ws[OFF_PREV + tid]   = lastpos[tid];
    ws[OFF_CURABS + tid] = obs[7 * 1024 + tid];   // obs_traj_pos[-1]
  }
  if (tid < 32768) {
    ws[OFF_H  + tid] = h0[tid];
    ws[OFF_CS + tid] = c0[tid];
    ws[OFF_CTX + tid] = 0.f;
    int k = tid >> 8, g = tid & 255;
    ws[OFF_WIHT + tid] = W_ih[g * 128 + k];
  }
  if (tid < 16384) {
    int k = tid >> 8, g = tid & 255;
    ws[OFF_WHHT + tid] = W_hh[g * 64 + k];
  }
  if (tid < 128) {
    int d = tid >> 6, m = tid & 63;
    float s = 0.f;
    for (int e = 0; e < 32; ++e) s += W_sp[d * 32 + e] * W1[e * 64 + m];
    ws[OFF_WC + tid] = s;
  }
  if (tid < 64) {
    float s = b1[tid];
    for (int e = 0; e < 32; ++e) s += b_sp[e] * W1[e * 64 + tid];
    ws[OFF_BASE + tid] = s;
  }
}

// Per-row phase: emb -> relu(emb@W_in) -> LSTM -> h,c ; A = h@W1_hj, B = h@W1_hi
// 4 rows per block, grid = 128
__global__ __launch_bounds__(256) void row_step(
    const float* __restrict__ cc, const float* __restrict__ zz,
    const float* __restrict__ W_in, const float* __restrict__ b_in,
    const float* __restrict__ b_ih, const float* __restrict__ b_hh,
    const float* __restrict__ W1, float* __restrict__ ws) {
  __shared__ float emb_t[162][4];
  __shared__ float h_t[64][4];
  __shared__ float x_t[128][4];
  __shared__ float gl[4][260];
  __shared__ float hn_t[64][4];
  int tid = threadIdx.x;
  int r0 = blockIdx.x * 4;
  const float* prev = ws + OFF_PREV;
  const float* ctx  = ws + OFF_CTX;
  float* hb  = ws + OFF_H;
  float* csb = ws + OFF_CS;

  for (int e = tid; e < 648; e += 256) {
    int d = e >> 2, r = e & 3, row = r0 + r;
    float v;
    if (d < 2)        v = prev[row * 2 + d];
    else if (d < 66)  v = cc[row * 64 + (d - 2)];
    else if (d < 98)  v = zz[row * 32 + (d - 66)];
    else              v = ctx[row * 64 + (d - 98)];
    emb_t[d][r] = v;
  }
  {
    int k = tid >> 2, r = tid & 3;
    h_t[k][r] = hb[(r0 + r) * 64 + k];
  }
  __syncthreads();
  // phase 1: x = relu(emb @ W_in + b_in)
  {
    int k = tid & 127, rh = tid >> 7;  // rh uniform per wave
    float a0 = b_in[k], a1 = a0;
    for (int d = 0; d < 162; ++d) {
      float w = W_in[d * 128 + k];
      a0 += emb_t[d][rh * 2 + 0] * w;
      a1 += emb_t[d][rh * 2 + 1] * w;
    }
    x_t[k][rh * 2 + 0] = fmaxf(a0, 0.f);
    x_t[k][rh * 2 + 1] = fmaxf(a1, 0.f);
  }
  __syncthreads();
  // phase 2: gates = x@W_ih^T + h@W_hh^T + biases (transposed weights in ws)
  {
    int g = tid;
    const float* wiht = ws + OFF_WIHT;
    const float* whht = ws + OFF_WHHT;
    float bias = b_ih[g] + b_hh[g];
    float ax = bias, ay = bias, az = bias, aw = bias;
    for (int kk = 0; kk < 128; ++kk) {
      float4 xv = *(const float4*)&x_t[kk][0];
      float w = wiht[kk * 256 + g];
      ax += xv.x * w; ay += xv.y * w; az += xv.z * w; aw += xv.w * w;
    }
    for (int kk = 0; kk < 64; ++kk) {
      float4 hv = *(const float4*)&h_t[kk][0];
      float w = whht[kk * 256 + g];
      ax += hv.x * w; ay += hv.y * w; az += hv.z * w; aw += hv.w * w;
    }
    gl[0][g] = ax; gl[1][g] = ay; gl[2][g] = az; gl[3][g] = aw;
  }
  __syncthreads();
  // phase 3: LSTM state update
  {
    int r = tid >> 6, u = tid & 63, row = r0 + r;
    float ig = gl[r][u], fg = gl[r][64 + u], gg = gl[r][128 + u], og = gl[r][192 + u];
    float is = 1.f / (1.f + expf(-ig));
    float fs = 1.f / (1.f + expf(-fg));
    float os = 1.f / (1.f + expf(-og));
    float cv = csb[row * 64 + u];
    float cn = fs * cv + is * tanhf(gg);
    csb[row * 64 + u] = cn;
    float hn = os * tanhf(cn);
    hb[row * 64 + u] = hn;
    hn_t[u][r] = hn;
  }
  __syncthreads();
  // phase 4: A = h@W1[32:96], B = h@W1[96:160]
  {
    int m = tid & 63, q = tid >> 6;       // q uniform per wave
    int which = q >> 1, rp = q & 1;
    float a0 = 0.f, a1 = 0.f;
    const float* wbase = W1 + (32 + which * 64) * 64 + m;
    for (int k = 0; k < 64; ++k) {
      float w = wbase[k * 64];
      a0 += hn_t[k][rp * 2 + 0] * w;
      a1 += hn_t[k][rp * 2 + 1] * w;
    }
    float* dst = ws + (which ? OFF_B : OFF_A);
    dst[(r0 + rp * 2 + 0) * 64 + m] = a0;
    dst[(r0 + rp * 2 + 1) * 64 + m] = a1;
  }
}

// Pooling + epilogue: one block per pedestrian i, grid = 512
__global__ __launch_bounds__(256) void pool_step(
    const int* __restrict__ nei, const float* __restrict__ epsin,
    const float* __restrict__ W2, const float* __restrict__ b2,
    const float* __restrict__ Wl2p, const float* __restrict__ bl2p,
    float* __restrict__ out, float* __restrict__ ws, int st) {
  __shared__ float h1[64][68];
  __shared__ float bib[64];
  __shared__ float wcl[128];
  __shared__ float cxl[64], cyl[64];
  __shared__ int   ml[64];
  __shared__ float red[4][64];
  __shared__ float ctxl[64], hl[64];
  __shared__ float posi[2];
  int tid = threadIdx.x;
  int i = blockIdx.x;
  int lane = tid & 63, w = tid >> 6;
  int rb = st & 1, wb = rb ^ 1;
  const float* curabs  = ws + OFF_CURABS + rb * 1024;
  float*       curabsw = ws + OFF_CURABS + wb * 1024;

  float W2col[64];
  #pragma unroll
  for (int m = 0; m < 64; ++m) W2col[m] = W2[m * 64 + lane];
  float b2n = b2[lane];

  if (tid < 64)        bib[tid] = ws[OFF_B + i * 64 + tid] + ws[OFF_BASE + tid];
  else if (tid < 192)  wcl[tid - 64] = ws[OFF_WC + (tid - 64)];
  else if (tid < 194)  posi[tid - 192] = curabs[i * 2 + (tid - 192)];
  __syncthreads();
  float px = posi[0], py = posi[1];
  float pmax = 0.f;   // h2 = relu(..) >= 0; "no valid neighbor -> 0" folds into init 0
  const float* Aws = ws + OFF_A;
  const int* neirow = nei + ((size_t)st * NP + i) * NP;

  for (int jt = 0; jt < 8; ++jt) {
    int j0 = jt * 64;
    if (tid < 64) {
      int jg = j0 + tid;
      cxl[tid] = px - curabs[jg * 2];
      cyl[tid] = py - curabs[jg * 2 + 1];
      ml[tid]  = neirow[jg];
    }
    __syncthreads();
    // h1 build: wave w builds rows j = 4p + w (mask uniform per wave)
    for (int p = 0; p < 16; ++p) {
      int j = p * 4 + w;
      if (ml[j] > 0) {
        float v = cxl[j] * wcl[lane] + cyl[j] * wcl[64 + lane] +
                  Aws[(j0 + j) * 64 + lane] + bib[lane];
        h1[j][lane] = fmaxf(v, 0.f);
      }
    }
    __syncthreads();
    // h2 = relu(h1 @ W2 + b2); masked running max. j uniform per wave.
    for (int jj = 0; jj < 16; ++jj) {
      int j = w * 16 + jj;
      if (ml[j] > 0) {
        const float4* hp = (const float4*)&h1[j][0];
        float acc = b2n;
        #pragma unroll
        for (int mq = 0; mq < 16; ++mq) {
          float4 hv = hp[mq];
          acc += hv.x * W2col[mq * 4 + 0] + hv.y * W2col[mq * 4 + 1] +
                 hv.z * W2col[mq * 4 + 2] + hv.w * W2col[mq * 4 + 3];
        }
        pmax = fmaxf(pmax, fmaxf(acc, 0.f));
      }
    }
    __syncthreads();
  }
  red[w][lane] = pmax;
  __syncthreads();
  if (tid < 64) {
    float m4 = fmaxf(fmaxf(red[0][tid], red[1][tid]),
                     fmaxf(red[2][tid], red[3][tid]));
    ws[OFF_CTX + i * 64 + tid] = m4;
    ctxl[tid] = m4;
    hl[tid] = ws[OFF_H + i * 64 + tid];
  }
  __syncthreads();
  if (tid < 64) {
    int l = tid;
    float cl = ctxl[l];
    float sc0 = cl * Wl2p[(32 + l) * 2 + 0];
    float sc1 = cl * Wl2p[(32 + l) * 2 + 1];
    float m0 = 0.f, m1 = 0.f, v0 = 0.f, v1 = 0.f;
    if (l < 32) {
      float hm = hl[l];
      m0 = hm * Wl2p[l * 2 + 0]; m1 = hm * Wl2p[l * 2 + 1];
      float hv = hl[32 + l];
      v0 = hv * Wl2p[l * 2 + 0]; v1 = hv * Wl2p[l * 2 + 1];
    }
    for (int off = 32; off >= 1; off >>= 1) {
      sc0 += __shfl_down(sc0, off);
      sc1 += __shfl_down(sc1, off);
      m0  += __shfl_down(m0,  off);
      m1  += __shfl_down(m1,  off);
      v0  += __shfl_down(v0,  off);
      v1  += __shfl_down(v1,  off);
    }
    if (l == 0) {
      float mu0 = m0 + sc0 + bl2p[0], mu1 = m1 + sc1 + bl2p[1];
      float lv0 = v0 + sc0 + bl2p[0], lv1 = v1 + sc1 + bl2p[1];
      float e0 = epsin[st * 1024 + i * 2 + 0];
      float e1 = epsin[st * 1024 + i * 2 + 1];
      float p0 = mu0 + e0 * expf(0.5f * lv0);
      float p1 = mu1 + e1 * expf(0.5f * lv1);
      out[st * 1024 + i * 2 + 0] = p0;
      out[st * 1024 + i * 2 + 1] = p1;
      out[12288 + st * 1024 + i * 2 + 0] = mu0;
      out[12288 + st * 1024 + i * 2 + 1] = mu1;
      out[24576 + st * 1024 + i * 2 + 0] = lv0;
      out[24576 + st * 1024 + i * 2 + 1] = lv1;
      curabsw[i * 2 + 0] = px + p0;
      curabsw[i * 2 + 1] = py + p1;
      ws[OFF_PREV + i * 2 + 0] = p0;
      ws[OFF_PREV + i * 2 + 1] = p1;
    }
  }
}

extern "C" void kernel_launch(void* const* d_in, const int* in_sizes, int n_in,
                              void* d_out, int out_size, void* d_ws, size_t ws_size,
                              hipStream_t stream) {
  const float* lastpos = (const float*)d_in[0];
  const float* cc      = (const float*)d_in[1];
  const float* zz      = (const float*)d_in[2];
  const float* obs     = (const float*)d_in[3];
  const int*   nei     = (const int*)d_in[4];
  // d_in[5] nei_num_index: unused by reference
  const float* h0      = (const float*)d_in[6];
  const float* c0      = (const float*)d_in[7];
  const float* eps     = (const float*)d_in[8];
  const float* W_in    = (const float*)d_in[9];
  const float* b_in    = (const float*)d_in[10];
  const float* W_ih    = (const float*)d_in[11];
  const float* W_hh    = (const float*)d_in[12];
  const float* b_ih    = (const float*)d_in[13];
  const float* b_hh    = (const float*)d_in[14];
  const float* W_l2p   = (const float*)d_in[15];
  const float* b_l2p   = (const float*)d_in[16];
  const float* W_sp    = (const float*)d_in[17];
  const float* b_sp    = (const float*)d_in[18];
  const float* W1      = (const float*)d_in[19];
  const float* b1      = (const float*)d_in[20];
  const float* W2      = (const float*)d_in[21];
  const float* b2      = (const float*)d_in[22];
  float* out = (float*)d_out;
  float* ws  = (float*)d_ws;

  hipLaunchKernelGGL(init_k, dim3(128), dim3(256), 0, stream,
                     lastpos, obs, h0, c0, W_ih, W_hh, W_sp, b_sp, W1, b1, ws);
  for (int st = 0; st < TT; ++st) {
    hipLaunchKernelGGL(row_step, dim3(128), dim3(256), 0, stream,
                       cc, zz, W_in, b_in, b_ih, b_hh, W1, ws);
    hipLaunchKernelGGL(pool_step, dim3(512), dim3(256), 0, stream,
                       nei, eps, W2, b2, W_l2p, b_l2p, out, ws, st);
  }
}

// Round 2
// 479.410 us; speedup vs baseline: 2.0245x; 2.0245x over previous
//
#include <hip/hip_runtime.h>
#include <math.h>

#define NP 512
#define TT 12

typedef float f32x4 __attribute__((ext_vector_type(4)));
typedef __bf16 bf16x8 __attribute__((ext_vector_type(8)));

// workspace float offsets
#define OFF_PREV   0        // N*2
#define OFF_CURABS 1024     // [2][N*2] double buffer
#define OFF_H      3072     // N*64
#define OFF_CS     35840    // N*64
#define OFF_CTX    68608    // N*64
#define OFF_A      101376   // N*64  (h @ W1[32:96] + base)  == "AB"
#define OFF_B      134144   // N*64  (h @ W1[96:160])
#define OFF_WIHT   166912   // 128*256 transposed W_ih
#define OFF_WHHT   199680   // 64*256 transposed W_hh
#define OFF_WC     216064   // [2][64]  W_sp @ W1[0:32]
#define OFF_BASE   216192   // [64]     b1 + b_sp @ W1[0:32]
// total 216256 floats = 865 KB

__global__ __launch_bounds__(256) void init_k(
    const float* __restrict__ lastpos, const float* __restrict__ obs,
    const float* __restrict__ h0, const float* __restrict__ c0,
    const float* __restrict__ W_ih, const float* __restrict__ W_hh,
    const float* __restrict__ W_sp, const float* __restrict__ b_sp,
    const float* __restrict__ W1, const float* __restrict__ b1,
    float* __restrict__ ws) {
  int tid = blockIdx.x * 256 + threadIdx.x;   // 128 blocks -> 32768 threads
  if (tid < 1024) {
    ws[OFF_PREV + tid]   = lastpos[tid];
    ws[OFF_CURABS + tid] = obs[7 * 1024 + tid];   // obs_traj_pos[-1]
  }
  if (tid < 32768) {
    ws[OFF_H  + tid] = h0[tid];
    ws[OFF_CS + tid] = c0[tid];
    ws[OFF_CTX + tid] = 0.f;
    int k = tid >> 8, g = tid & 255;
    ws[OFF_WIHT + tid] = W_ih[g * 128 + k];
  }
  if (tid < 16384) {
    int k = tid >> 8, g = tid & 255;
    ws[OFF_WHHT + tid] = W_hh[g * 64 + k];
  }
  if (tid < 128) {
    int d = tid >> 6, m = tid & 63;
    float s = 0.f;
    for (int e = 0; e < 32; ++e) s += W_sp[d * 32 + e] * W1[e * 64 + m];
    ws[OFF_WC + tid] = s;
  }
  if (tid < 64) {
    float s = b1[tid];
    for (int e = 0; e < 32; ++e) s += b_sp[e] * W1[e * 64 + tid];
    ws[OFF_BASE + tid] = s;
  }
}

// Per-row phase: one row per block, grid = 512.
__global__ __launch_bounds__(256) void row_step(
    const float* __restrict__ cc, const float* __restrict__ zz,
    const float* __restrict__ W_in, const float* __restrict__ b_in,
    const float* __restrict__ b_ih, const float* __restrict__ b_hh,
    const float* __restrict__ W1, float* __restrict__ ws) {
  __shared__ float emb[162];
  __shared__ float hvec[64];
  __shared__ float xpart[2][128];
  __shared__ float xvec[128];
  __shared__ float gl[256];
  __shared__ float hn[64];
  int t = threadIdx.x;
  int row = blockIdx.x;

  if (t < 162) {
    float v;
    if (t < 2)       v = ws[OFF_PREV + row * 2 + t];
    else if (t < 66) v = cc[row * 64 + (t - 2)];
    else if (t < 98) v = zz[row * 32 + (t - 66)];
    else             v = ws[OFF_CTX + row * 64 + (t - 98)];
    emb[t] = v;
  } else if (t < 226) {
    hvec[t - 162] = ws[OFF_H + row * 64 + (t - 162)];
  }
  __syncthreads();
  // phase 1: x = relu(emb@W_in + b_in), split-K 2 ways, 2 accumulators
  {
    int k = t & 127, p = t >> 7;
    float a0 = 0.f, a1 = 0.f;
    int d = p;
    for (; d + 2 < 162; d += 4) {
      a0 = fmaf(emb[d],     W_in[d * 128 + k],       a0);
      a1 = fmaf(emb[d + 2], W_in[(d + 2) * 128 + k], a1);
    }
    if (d < 162) a0 = fmaf(emb[d], W_in[d * 128 + k], a0);
    xpart[p][k] = a0 + a1;
  }
  __syncthreads();
  if (t < 128) xvec[t] = fmaxf(xpart[0][t] + xpart[1][t] + b_in[t], 0.f);
  __syncthreads();
  // phase 2: gates, 4 independent accumulators
  {
    int g = t;
    const float* wiht = ws + OFF_WIHT;
    const float* whht = ws + OFF_WHHT;
    float s0 = 0.f, s1 = 0.f, s2 = 0.f, s3 = 0.f;
    for (int kk = 0; kk < 128; kk += 4) {
      s0 = fmaf(xvec[kk],     wiht[kk * 256 + g],       s0);
      s1 = fmaf(xvec[kk + 1], wiht[(kk + 1) * 256 + g], s1);
      s2 = fmaf(xvec[kk + 2], wiht[(kk + 2) * 256 + g], s2);
      s3 = fmaf(xvec[kk + 3], wiht[(kk + 3) * 256 + g], s3);
    }
    for (int kk = 0; kk < 64; kk += 4) {
      s0 = fmaf(hvec[kk],     whht[kk * 256 + g],       s0);
      s1 = fmaf(hvec[kk + 1], whht[(kk + 1) * 256 + g], s1);
      s2 = fmaf(hvec[kk + 2], whht[(kk + 2) * 256 + g], s2);
      s3 = fmaf(hvec[kk + 3], whht[(kk + 3) * 256 + g], s3);
    }
    gl[g] = b_ih[g] + b_hh[g] + ((s0 + s1) + (s2 + s3));
  }
  __syncthreads();
  // phase 3: LSTM state update
  if (t < 64) {
    float ig = gl[t], fg = gl[64 + t], gg = gl[128 + t], og = gl[192 + t];
    float is = 1.f / (1.f + expf(-ig));
    float fs = 1.f / (1.f + expf(-fg));
    float os = 1.f / (1.f + expf(-og));
    float cv = ws[OFF_CS + row * 64 + t];
    float cn = fs * cv + is * tanhf(gg);
    ws[OFF_CS + row * 64 + t] = cn;
    float hv = os * tanhf(cn);
    ws[OFF_H + row * 64 + t] = hv;
    hn[t] = hv;
  }
  __syncthreads();
  // phase 4: AB = h@W1[32:96]+base ; B = h@W1[96:160]
  if (t < 128) {
    int which = t >> 6, m = t & 63;
    const float* wb = W1 + (32 + which * 64) * 64 + m;
    float s0 = 0.f, s1 = 0.f, s2 = 0.f, s3 = 0.f;
    for (int k = 0; k < 64; k += 4) {
      s0 = fmaf(hn[k],     wb[k * 64],       s0);
      s1 = fmaf(hn[k + 1], wb[(k + 1) * 64], s1);
      s2 = fmaf(hn[k + 2], wb[(k + 2) * 64], s2);
      s3 = fmaf(hn[k + 3], wb[(k + 3) * 64], s3);
    }
    float s = (s0 + s1) + (s2 + s3);
    if (which == 0) ws[OFF_A + row * 64 + m] = s + ws[OFF_BASE + m];
    else            ws[OFF_B + row * 64 + m] = s;
  }
}

// Pooling + epilogue: one block per pedestrian i, grid = 512, 4 waves.
__global__ __launch_bounds__(256) void pool_step(
    const int* __restrict__ nei, const float* __restrict__ epsin,
    const float* __restrict__ W2, const float* __restrict__ b2,
    const float* __restrict__ Wl2p, const float* __restrict__ bl2p,
    float* __restrict__ out, float* __restrict__ ws, int st) {
  __shared__ __align__(16) __bf16 h1buf[4][32 * 72];   // per-wave tiles, pad 72
  __shared__ __align__(16) __bf16 W2T[64 * 72];        // [m][k], pad 72
  __shared__ float absx[512], absy[512];
  __shared__ int   ml[512];
  __shared__ float bib[64], wcl[128];
  __shared__ float red[4][64];
  __shared__ float ctxl[64], hl[64];
  int tid = threadIdx.x;
  int i = blockIdx.x;
  int lane = tid & 63, w = tid >> 6;
  int quad = lane >> 4, col = lane & 15;
  int rb = st & 1, wbuf = rb ^ 1;
  const float* curabs  = ws + OFF_CURABS + rb * 1024;
  float*       curabsw = ws + OFF_CURABS + wbuf * 1024;
  const int* neirow = nei + ((size_t)st * NP + i) * NP;

  {
    const float2* ca = (const float2*)curabs;
    for (int j = tid; j < 512; j += 256) {
      float2 p = ca[j];
      absx[j] = p.x; absy[j] = p.y;
      ml[j] = neirow[j];
    }
    if (tid < 64)       bib[tid] = ws[OFF_B + i * 64 + tid];
    else if (tid < 192) wcl[tid - 64] = ws[OFF_WC + (tid - 64)];
    for (int e = tid; e < 4096; e += 256)
      W2T[(e & 63) * 72 + (e >> 6)] = (__bf16)W2[e];
  }
  __syncthreads();

  float px = absx[i], py = absy[i];
  float wcx = wcl[lane], wcy = wcl[64 + lane];
  float bi  = bib[lane];
  float b2v0 = b2[col], b2v1 = b2[16 + col], b2v2 = b2[32 + col], b2v3 = b2[48 + col];
  bf16x8 bf00 = *(const bf16x8*)&W2T[(0 * 16 + col) * 72 + 0 * 32 + quad * 8];
  bf16x8 bf01 = *(const bf16x8*)&W2T[(0 * 16 + col) * 72 + 1 * 32 + quad * 8];
  bf16x8 bf10 = *(const bf16x8*)&W2T[(1 * 16 + col) * 72 + 0 * 32 + quad * 8];
  bf16x8 bf11 = *(const bf16x8*)&W2T[(1 * 16 + col) * 72 + 1 * 32 + quad * 8];
  bf16x8 bf20 = *(const bf16x8*)&W2T[(2 * 16 + col) * 72 + 0 * 32 + quad * 8];
  bf16x8 bf21 = *(const bf16x8*)&W2T[(2 * 16 + col) * 72 + 1 * 32 + quad * 8];
  bf16x8 bf30 = *(const bf16x8*)&W2T[(3 * 16 + col) * 72 + 0 * 32 + quad * 8];
  bf16x8 bf31 = *(const bf16x8*)&W2T[(3 * 16 + col) * 72 + 1 * 32 + quad * 8];

  float vmax0 = 0.f, vmax1 = 0.f, vmax2 = 0.f, vmax3 = 0.f;
  __bf16* myh1 = h1buf[w];
  const float* Aws = ws + OFF_A;

  for (int c = 0; c < 4; ++c) {
    int jbase = w * 128 + c * 32;
    #pragma unroll 4
    for (int j = 0; j < 32; ++j) {
      int jg = jbase + j;
      float v = fmaf(px - absx[jg], wcx,
                fmaf(py - absy[jg], wcy, Aws[jg * 64 + lane] + bi));
      myh1[j * 72 + lane] = (__bf16)fmaxf(v, 0.f);
    }
    #pragma unroll
    for (int js = 0; js < 2; ++js) {
      bf16x8 a0 = *(const bf16x8*)&myh1[(js * 16 + col) * 72 + 0 * 32 + quad * 8];
      bf16x8 a1 = *(const bf16x8*)&myh1[(js * 16 + col) * 72 + 1 * 32 + quad * 8];
      int rowb = jbase + js * 16 + quad * 4;
      bool mk0 = ml[rowb] > 0, mk1 = ml[rowb + 1] > 0,
           mk2 = ml[rowb + 2] > 0, mk3 = ml[rowb + 3] > 0;
      f32x4 acc;
      acc = (f32x4){0.f, 0.f, 0.f, 0.f};
      acc = __builtin_amdgcn_mfma_f32_16x16x32_bf16(a0, bf00, acc, 0, 0, 0);
      acc = __builtin_amdgcn_mfma_f32_16x16x32_bf16(a1, bf01, acc, 0, 0, 0);
      vmax0 = fmaxf(vmax0, mk0 ? acc[0] + b2v0 : 0.f);
      vmax0 = fmaxf(vmax0, mk1 ? acc[1] + b2v0 : 0.f);
      vmax0 = fmaxf(vmax0, mk2 ? acc[2] + b2v0 : 0.f);
      vmax0 = fmaxf(vmax0, mk3 ? acc[3] + b2v0 : 0.f);
      acc = (f32x4){0.f, 0.f, 0.f, 0.f};
      acc = __builtin_amdgcn_mfma_f32_16x16x32_bf16(a0, bf10, acc, 0, 0, 0);
      acc = __builtin_amdgcn_mfma_f32_16x16x32_bf16(a1, bf11, acc, 0, 0, 0);
      vmax1 = fmaxf(vmax1, mk0 ? acc[0] + b2v1 : 0.f);
      vmax1 = fmaxf(vmax1, mk1 ? acc[1] + b2v1 : 0.f);
      vmax1 = fmaxf(vmax1, mk2 ? acc[2] + b2v1 : 0.f);
      vmax1 = fmaxf(vmax1, mk3 ? acc[3] + b2v1 : 0.f);
      acc = (f32x4){0.f, 0.f, 0.f, 0.f};
      acc = __builtin_amdgcn_mfma_f32_16x16x32_bf16(a0, bf20, acc, 0, 0, 0);
      acc = __builtin_amdgcn_mfma_f32_16x16x32_bf16(a1, bf21, acc, 0, 0, 0);
      vmax2 = fmaxf(vmax2, mk0 ? acc[0] + b2v2 : 0.f);
      vmax2 = fmaxf(vmax2, mk1 ? acc[1] + b2v2 : 0.f);
      vmax2 = fmaxf(vmax2, mk2 ? acc[2] + b2v2 : 0.f);
      vmax2 = fmaxf(vmax2, mk3 ? acc[3] + b2v2 : 0.f);
      acc = (f32x4){0.f, 0.f, 0.f, 0.f};
      acc = __builtin_amdgcn_mfma_f32_16x16x32_bf16(a0, bf30, acc, 0, 0, 0);
      acc = __builtin_amdgcn_mfma_f32_16x16x32_bf16(a1, bf31, acc, 0, 0, 0);
      vmax3 = fmaxf(vmax3, mk0 ? acc[0] + b2v3 : 0.f);
      vmax3 = fmaxf(vmax3, mk1 ? acc[1] + b2v3 : 0.f);
      vmax3 = fmaxf(vmax3, mk2 ? acc[2] + b2v3 : 0.f);
      vmax3 = fmaxf(vmax3, mk3 ? acc[3] + b2v3 : 0.f);
    }
  }
  vmax0 = fmaxf(vmax0, __shfl_xor(vmax0, 16));
  vmax0 = fmaxf(vmax0, __shfl_xor(vmax0, 32));
  vmax1 = fmaxf(vmax1, __shfl_xor(vmax1, 16));
  vmax1 = fmaxf(vmax1, __shfl_xor(vmax1, 32));
  vmax2 = fmaxf(vmax2, __shfl_xor(vmax2, 16));
  vmax2 = fmaxf(vmax2, __shfl_xor(vmax2, 32));
  vmax3 = fmaxf(vmax3, __shfl_xor(vmax3, 16));
  vmax3 = fmaxf(vmax3, __shfl_xor(vmax3, 32));
  if (lane < 16) {
    red[w][0 * 16 + lane] = vmax0;
    red[w][1 * 16 + lane] = vmax1;
    red[w][2 * 16 + lane] = vmax2;
    red[w][3 * 16 + lane] = vmax3;
  }
  __syncthreads();
  if (tid < 64) {
    float m4 = fmaxf(fmaxf(red[0][tid], red[1][tid]),
                     fmaxf(red[2][tid], red[3][tid]));
    ws[OFF_CTX + i * 64 + tid] = m4;
    ctxl[tid] = m4;
    hl[tid] = ws[OFF_H + i * 64 + tid];
  }
  __syncthreads();
  if (tid < 64) {
    int l = tid;
    float cl = ctxl[l];
    float sc0 = cl * Wl2p[(32 + l) * 2 + 0];
    float sc1 = cl * Wl2p[(32 + l) * 2 + 1];
    float m0 = 0.f, m1 = 0.f, v0 = 0.f, v1 = 0.f;
    if (l < 32) {
      float hm = hl[l];
      m0 = hm * Wl2p[l * 2 + 0]; m1 = hm * Wl2p[l * 2 + 1];
      float hv = hl[32 + l];
      v0 = hv * Wl2p[l * 2 + 0]; v1 = hv * Wl2p[l * 2 + 1];
    }
    for (int off = 32; off >= 1; off >>= 1) {
      sc0 += __shfl_down(sc0, off);
      sc1 += __shfl_down(sc1, off);
      m0  += __shfl_down(m0,  off);
      m1  += __shfl_down(m1,  off);
      v0  += __shfl_down(v0,  off);
      v1  += __shfl_down(v1,  off);
    }
    if (l == 0) {
      float mu0 = m0 + sc0 + bl2p[0], mu1 = m1 + sc1 + bl2p[1];
      float lv0 = v0 + sc0 + bl2p[0], lv1 = v1 + sc1 + bl2p[1];
      float e0 = epsin[st * 1024 + i * 2 + 0];
      float e1 = epsin[st * 1024 + i * 2 + 1];
      float p0 = mu0 + e0 * expf(0.5f * lv0);
      float p1 = mu1 + e1 * expf(0.5f * lv1);
      out[st * 1024 + i * 2 + 0] = p0;
      out[st * 1024 + i * 2 + 1] = p1;
      out[12288 + st * 1024 + i * 2 + 0] = mu0;
      out[12288 + st * 1024 + i * 2 + 1] = mu1;
      out[24576 + st * 1024 + i * 2 + 0] = lv0;
      out[24576 + st * 1024 + i * 2 + 1] = lv1;
      curabsw[i * 2 + 0] = px + p0;
      curabsw[i * 2 + 1] = py + p1;
      ws[OFF_PREV + i * 2 + 0] = p0;
      ws[OFF_PREV + i * 2 + 1] = p1;
    }
  }
}

extern "C" void kernel_launch(void* const* d_in, const int* in_sizes, int n_in,
                              void* d_out, int out_size, void* d_ws, size_t ws_size,
                              hipStream_t stream) {
  const float* lastpos = (const float*)d_in[0];
  const float* cc      = (const float*)d_in[1];
  const float* zz      = (const float*)d_in[2];
  const float* obs     = (const float*)d_in[3];
  const int*   nei     = (const int*)d_in[4];
  const float* h0      = (const float*)d_in[6];
  const float* c0      = (const float*)d_in[7];
  const float* eps     = (const float*)d_in[8];
  const float* W_in    = (const float*)d_in[9];
  const float* b_in    = (const float*)d_in[10];
  const float* W_ih    = (const float*)d_in[11];
  const float* W_hh    = (const float*)d_in[12];
  const float* b_ih    = (const float*)d_in[13];
  const float* b_hh    = (const float*)d_in[14];
  const float* W_l2p   = (const float*)d_in[15];
  const float* b_l2p   = (const float*)d_in[16];
  const float* W_sp    = (const float*)d_in[17];
  const float* b_sp    = (const float*)d_in[18];
  const float* W1      = (const float*)d_in[19];
  const float* b1      = (const float*)d_in[20];
  const float* W2      = (const float*)d_in[21];
  const float* b2      = (const float*)d_in[22];
  float* out = (float*)d_out;
  float* ws  = (float*)d_ws;

  hipLaunchKernelGGL(init_k, dim3(128), dim3(256), 0, stream,
                     lastpos, obs, h0, c0, W_ih, W_hh, W_sp, b_sp, W1, b1, ws);
  for (int st = 0; st < TT; ++st) {
    hipLaunchKernelGGL(row_step, dim3(512), dim3(256), 0, stream,
                       cc, zz, W_in, b_in, b_ih, b_hh, W1, ws);
    hipLaunchKernelGGL(pool_step, dim3(512), dim3(256), 0, stream,
                       nei, eps, W2, b2, W_l2p, b_l2p, out, ws, st);
  }
}